// Round 1
// baseline (221.777 us; speedup 1.0000x reference)
//
#include <hip/hip_runtime.h>

typedef __attribute__((ext_vector_type(8))) __bf16 bf16x8;
typedef __attribute__((ext_vector_type(4))) __bf16 bf16x4;
typedef __attribute__((ext_vector_type(4))) float f32x4;

#define MFMA16x16x32(A, B, C) __builtin_amdgcn_mfma_f32_16x16x32_bf16(A, B, C, 0, 0, 0)

__device__ __forceinline__ unsigned short f2bf(float f) {
    unsigned int u = __float_as_uint(f);
    u += 0x7fffu + ((u >> 16) & 1u);
    return (unsigned short)(u >> 16);
}

__device__ __forceinline__ void gload16(const void* src, void* lds) {
    __builtin_amdgcn_global_load_lds(
        (const __attribute__((address_space(1))) unsigned int*)src,
        (__attribute__((address_space(3))) unsigned int*)lds,
        16, 0, 0);
}

// ---------------- stage 1: x fp32 -> bf16 ----------------
__global__ __launch_bounds__(256) void cvt_x_kernel(const float* __restrict__ x,
                                                    unsigned short* __restrict__ xb) {
    const int i = (blockIdx.x * 256 + threadIdx.x) * 4;
    const float4 v = *(const float4*)(x + i);
    ushort4 o;
    o.x = f2bf(v.x); o.y = f2bf(v.y); o.z = f2bf(v.z); o.w = f2bf(v.w);
    *(ushort4*)(xb + i) = o;
}

// ---------------- stage 2: W [K][N] fp32 -> Wt [N][K=1024] bf16 ----------------
__global__ __launch_bounds__(256) void tr_w_kernel(const float* __restrict__ W,
                                                   unsigned short* __restrict__ Wt, int N) {
    __shared__ float tile[32][33];
    const int k0 = blockIdx.x * 32;
    const int n0 = blockIdx.y * 32;
    const int tx = threadIdx.x, ty = threadIdx.y;
#pragma unroll
    for (int i = 0; i < 4; ++i)
        tile[ty + 8 * i][tx] = W[(size_t)(k0 + ty + 8 * i) * N + n0 + tx];
    __syncthreads();
#pragma unroll
    for (int i = 0; i < 4; ++i)
        Wt[(size_t)(n0 + ty + 8 * i) * 1024 + k0 + tx] = f2bf(tile[tx][ty + 8 * i]);
}

// ---------------- stage 4: V [bh][s][64] -> Vt [bh][64][s] (bf16) ----------------
__global__ __launch_bounds__(256) void tr_v_kernel(const unsigned short* __restrict__ Vb,
                                                   unsigned short* __restrict__ Vt) {
    __shared__ unsigned short tile[32][33];
    const int bh = blockIdx.z;
    const int s0 = blockIdx.x * 32;
    const int d0 = blockIdx.y * 32;
    const int tx = threadIdx.x, ty = threadIdx.y;
#pragma unroll
    for (int i = 0; i < 4; ++i)
        tile[ty + 8 * i][tx] = Vb[((size_t)bh * 2048 + s0 + ty + 8 * i) * 64 + d0 + tx];
    __syncthreads();
#pragma unroll
    for (int i = 0; i < 4; ++i)
        Vt[((size_t)bh * 64 + d0 + ty + 8 * i) * 2048 + s0 + tx] = tile[tx][ty + 8 * i];
}

// ---------------- stage 3: fused QKV GEMM ----------------
// X [4096][1024] bf16  x  Wt [1024 n][1024 k] bf16  -> Q/K/V [b][h][s][d] bf16 (+bias)
// 128x128 tile, BK=32, 4 waves (2x2), dbuf global_load_lds w/ pre-swizzled source.
__global__ __launch_bounds__(256, 2) void gemm_qkv_kernel(
    const unsigned short* __restrict__ xb,
    const unsigned short* __restrict__ Wqt,
    const unsigned short* __restrict__ Wkt,
    const unsigned short* __restrict__ Wvt,
    const float* __restrict__ bq, const float* __restrict__ bk, const float* __restrict__ bv,
    unsigned short* __restrict__ Qb, unsigned short* __restrict__ Kb, unsigned short* __restrict__ Vb)
{
    __shared__ unsigned short sA[2][128 * 32];
    __shared__ unsigned short sB[2][128 * 32];

    const int tid  = threadIdx.x;
    const int lane = tid & 63;
    const int w    = tid >> 6;
    const int wm   = w >> 1, wn = w & 1;
    const int li   = lane & 15, gg = lane >> 4;
    const int m0   = blockIdx.y * 128;
    const int which = blockIdx.x >> 3;
    const int nloc0 = (blockIdx.x & 7) * 128;

    const unsigned short* Wt = (which == 0) ? Wqt : ((which == 1) ? Wkt : Wvt);
    const float* bias        = (which == 0) ? bq  : ((which == 1) ? bk  : bv);
    unsigned short* dst      = (which == 0) ? Qb  : ((which == 1) ? Kb  : Vb);

    const int srow = lane >> 2;   // row within 16-row chunk
    const int schk = lane & 3;    // 16B chunk within 64B row

    f32x4 acc[4][4];
#pragma unroll
    for (int i = 0; i < 4; ++i)
#pragma unroll
        for (int j = 0; j < 4; ++j)
            acc[i][j] = (f32x4){0.f, 0.f, 0.f, 0.f};

    // LDS read offsets (ushort units), XOR-swizzled: chunk ^= (row>>1)&3
    int aoff[4], boff[4];
#pragma unroll
    for (int f = 0; f < 4; ++f) {
        const int ra = wm * 64 + f * 16 + li;
        aoff[f] = ra * 32 + ((gg ^ ((ra >> 1) & 3)) * 8);
        const int rb = wn * 64 + f * 16 + li;
        boff[f] = rb * 32 + ((gg ^ ((rb >> 1) & 3)) * 8);
    }

    // prologue: stage kt=0
#pragma unroll
    for (int j = 0; j < 2; ++j) {
        const int rl = (w * 2 + j) * 16 + srow;
        const int c  = schk ^ ((rl >> 1) & 3);
        gload16(xb + (size_t)(m0 + rl) * 1024 + c * 8,   sA[0] + (w * 2 + j) * 512);
        gload16(Wt + (size_t)(nloc0 + rl) * 1024 + c * 8, sB[0] + (w * 2 + j) * 512);
    }
    __syncthreads();

    for (int kt = 0; kt < 32; ++kt) {
        const int cur = kt & 1;
        if (kt < 31) {
            const int k1 = (kt + 1) * 32;
#pragma unroll
            for (int j = 0; j < 2; ++j) {
                const int rl = (w * 2 + j) * 16 + srow;
                const int c  = schk ^ ((rl >> 1) & 3);
                gload16(xb + (size_t)(m0 + rl) * 1024 + k1 + c * 8,   sA[cur ^ 1] + (w * 2 + j) * 512);
                gload16(Wt + (size_t)(nloc0 + rl) * 1024 + k1 + c * 8, sB[cur ^ 1] + (w * 2 + j) * 512);
            }
        }
        bf16x8 av[4], bw[4];
#pragma unroll
        for (int f = 0; f < 4; ++f) av[f] = *(const bf16x8*)(sA[cur] + aoff[f]);
#pragma unroll
        for (int f = 0; f < 4; ++f) bw[f] = *(const bf16x8*)(sB[cur] + boff[f]);
#pragma unroll
        for (int mf = 0; mf < 4; ++mf)
#pragma unroll
            for (int nf = 0; nf < 4; ++nf)
                acc[mf][nf] = MFMA16x16x32(av[mf], bw[nf], acc[mf][nf]);
        __syncthreads();
    }

    // epilogue: C frag: col = lane&15, row = (lane>>4)*4 + r  [m89-verified]
#pragma unroll
    for (int nf = 0; nf < 4; ++nf) {
        const int nl = nloc0 + wn * 64 + nf * 16 + li;
        const float bi = bias[nl];
        const int h = nl >> 6, d = nl & 63;
#pragma unroll
        for (int mf = 0; mf < 4; ++mf) {
#pragma unroll
            for (int r = 0; r < 4; ++r) {
                const int m = m0 + wm * 64 + mf * 16 + gg * 4 + r;
                const int b = m >> 11, s = m & 2047;
                dst[(((size_t)(b * 16 + h)) * 2048 + s) * 64 + d] = f2bf(acc[mf][nf][r] + bi);
            }
        }
    }
}

// ---------------- stage 5: flash attention ----------------
// grid (16 q-tiles, 32 bh); 4 waves x 32 q-rows; KV tiles of 64, online softmax.
__global__ __launch_bounds__(256, 2) void attn_kernel(
    const unsigned short* __restrict__ Qb,
    const unsigned short* __restrict__ Kb,
    const unsigned short* __restrict__ Vt,
    unsigned short* __restrict__ Ob)
{
    __shared__ unsigned short sK[2][64 * 64];
    __shared__ unsigned short sV[2][64 * 64];
    __shared__ unsigned short sP[4][32 * 68];   // per-wave P tile, stride 68 (conflict-free)

    const int tid  = threadIdx.x;
    const int lane = tid & 63;
    const int w    = tid >> 6;
    const int li   = lane & 15, gg = lane >> 4;
    const int bh   = blockIdx.y;
    const int q0   = blockIdx.x * 128 + w * 32;

    const int srow8 = lane >> 3;
    const int sc8   = lane & 7;

    // Q fragments held in registers for the whole kernel
    bf16x8 qf[2][2];
#pragma unroll
    for (int mf = 0; mf < 2; ++mf)
#pragma unroll
        for (int kk = 0; kk < 2; ++kk) {
            const int q = q0 + mf * 16 + li;
            const int d = kk * 32 + gg * 8;
            qf[mf][kk] = *(const bf16x8*)(Qb + ((size_t)bh * 2048 + q) * 64 + d);
        }

    f32x4 acc[2][4];
    float mrow[2][4], lrow[2][4];
#pragma unroll
    for (int mf = 0; mf < 2; ++mf) {
#pragma unroll
        for (int df = 0; df < 4; ++df) acc[mf][df] = (f32x4){0.f, 0.f, 0.f, 0.f};
#pragma unroll
        for (int r = 0; r < 4; ++r) { mrow[mf][r] = -1e30f; lrow[mf][r] = 0.f; }
    }

    // prologue: stage tile 0
#pragma unroll
    for (int j = 0; j < 2; ++j) {
        const int rl = (w * 2 + j) * 8 + srow8;
        const int c  = sc8 ^ (rl & 7);
        gload16(Kb + ((size_t)bh * 2048 + rl) * 64 + c * 8, sK[0] + (w * 2 + j) * 512);
        gload16(Vt + ((size_t)bh * 64 + rl) * 2048 + c * 8, sV[0] + (w * 2 + j) * 512);
    }
    __syncthreads();

    const float cs = 0.18033688011112042f;  // log2(e) / sqrt(64)

    for (int t = 0; t < 32; ++t) {
        const int cur = t & 1;
        if (t < 31) {
#pragma unroll
            for (int j = 0; j < 2; ++j) {
                const int rl = (w * 2 + j) * 8 + srow8;
                const int c  = sc8 ^ (rl & 7);
                gload16(Kb + ((size_t)bh * 2048 + (t + 1) * 64 + rl) * 64 + c * 8,
                        sK[cur ^ 1] + (w * 2 + j) * 512);
                gload16(Vt + ((size_t)bh * 64 + rl) * 2048 + (t + 1) * 64 + c * 8,
                        sV[cur ^ 1] + (w * 2 + j) * 512);
            }
        }

        // ---- scores: S = Q K^T ----
        bf16x8 kf[4][2];
#pragma unroll
        for (int nf = 0; nf < 4; ++nf)
#pragma unroll
            for (int kk = 0; kk < 2; ++kk) {
                const int n = nf * 16 + li;
                const int ch = kk * 4 + gg;
                kf[nf][kk] = *(const bf16x8*)(sK[cur] + n * 64 + ((ch ^ (n & 7)) * 8));
            }
        f32x4 st[2][4];
#pragma unroll
        for (int mf = 0; mf < 2; ++mf)
#pragma unroll
            for (int nf = 0; nf < 4; ++nf) {
                st[mf][nf] = (f32x4){0.f, 0.f, 0.f, 0.f};
                st[mf][nf] = MFMA16x16x32(qf[mf][0], kf[nf][0], st[mf][nf]);
                st[mf][nf] = MFMA16x16x32(qf[mf][1], kf[nf][1], st[mf][nf]);
            }

        // ---- online softmax (row = (lane>>4)*4+r, reduce across lane&15) ----
#pragma unroll
        for (int mf = 0; mf < 2; ++mf) {
            float mnew[4], alpha[4], rs[4];
#pragma unroll
            for (int r = 0; r < 4; ++r) {
                float v = fmaxf(fmaxf(st[mf][0][r], st[mf][1][r]),
                                fmaxf(st[mf][2][r], st[mf][3][r]));
                v = fmaxf(v, __shfl_xor(v, 1, 64));
                v = fmaxf(v, __shfl_xor(v, 2, 64));
                v = fmaxf(v, __shfl_xor(v, 4, 64));
                v = fmaxf(v, __shfl_xor(v, 8, 64));
                v *= cs;
                mnew[r]  = fmaxf(mrow[mf][r], v);
                alpha[r] = exp2f(mrow[mf][r] - mnew[r]);
                mrow[mf][r] = mnew[r];
                rs[r] = 0.f;
            }
#pragma unroll
            for (int nf = 0; nf < 4; ++nf)
#pragma unroll
                for (int r = 0; r < 4; ++r) {
                    const float p = exp2f(st[mf][nf][r] * cs - mnew[r]);
                    st[mf][nf][r] = p;
                    rs[r] += p;
                }
#pragma unroll
            for (int r = 0; r < 4; ++r) {
                float t2 = rs[r];
                t2 += __shfl_xor(t2, 1, 64);
                t2 += __shfl_xor(t2, 2, 64);
                t2 += __shfl_xor(t2, 4, 64);
                t2 += __shfl_xor(t2, 8, 64);
                lrow[mf][r] = lrow[mf][r] * alpha[r] + t2;
            }
#pragma unroll
            for (int df = 0; df < 4; ++df)
#pragma unroll
                for (int r = 0; r < 4; ++r)
                    acc[mf][df][r] *= alpha[r];
            // store P tile (bf16) to per-wave LDS
#pragma unroll
            for (int nf = 0; nf < 4; ++nf)
#pragma unroll
                for (int r = 0; r < 4; ++r)
                    sP[w][(mf * 16 + gg * 4 + r) * 68 + nf * 16 + li] = f2bf(st[mf][nf][r]);
        }

        // ---- PV ----
        bf16x8 pf[2][2];
#pragma unroll
        for (int mf = 0; mf < 2; ++mf)
#pragma unroll
            for (int kk = 0; kk < 2; ++kk) {
                const unsigned short* pb = sP[w] + (mf * 16 + li) * 68 + kk * 32 + gg * 8;
                const bf16x4 lo = *(const bf16x4*)pb;
                const bf16x4 hi = *(const bf16x4*)(pb + 4);
                pf[mf][kk] = __builtin_shufflevector(lo, hi, 0, 1, 2, 3, 4, 5, 6, 7);
            }
        bf16x8 vf[4][2];
#pragma unroll
        for (int df = 0; df < 4; ++df)
#pragma unroll
            for (int kk = 0; kk < 2; ++kk) {
                const int n = df * 16 + li;
                const int ch = kk * 4 + gg;
                vf[df][kk] = *(const bf16x8*)(sV[cur] + n * 64 + ((ch ^ (n & 7)) * 8));
            }
#pragma unroll
        for (int mf = 0; mf < 2; ++mf)
#pragma unroll
            for (int df = 0; df < 4; ++df) {
                acc[mf][df] = MFMA16x16x32(pf[mf][0], vf[df][0], acc[mf][df]);
                acc[mf][df] = MFMA16x16x32(pf[mf][1], vf[df][1], acc[mf][df]);
            }
        __syncthreads();
    }

    // epilogue: O = acc / l  -> attn buffer [b][s][h][d] (bf16)
    const int b = bh >> 4, h = bh & 15;
#pragma unroll
    for (int mf = 0; mf < 2; ++mf)
#pragma unroll
        for (int df = 0; df < 4; ++df)
#pragma unroll
            for (int r = 0; r < 4; ++r) {
                const int q = q0 + mf * 16 + gg * 4 + r;
                const int d = df * 16 + li;
                const float o = acc[mf][df][r] / lrow[mf][r];
                Ob[(((size_t)b * 2048 + q) * 16 + h) * 64 + d] = f2bf(o);
            }
}

// ---------------- stage 6: output projection ----------------
__global__ __launch_bounds__(256, 2) void gemm_out_kernel(
    const unsigned short* __restrict__ attn,
    const unsigned short* __restrict__ Wot,
    const float* __restrict__ bo,
    float* __restrict__ out)
{
    __shared__ unsigned short sA[2][128 * 32];
    __shared__ unsigned short sB[2][128 * 32];

    const int tid  = threadIdx.x;
    const int lane = tid & 63;
    const int w    = tid >> 6;
    const int wm   = w >> 1, wn = w & 1;
    const int li   = lane & 15, gg = lane >> 4;
    const int m0   = blockIdx.y * 128;
    const int n0   = blockIdx.x * 128;

    const int srow = lane >> 2;
    const int schk = lane & 3;

    f32x4 acc[4][4];
#pragma unroll
    for (int i = 0; i < 4; ++i)
#pragma unroll
        for (int j = 0; j < 4; ++j)
            acc[i][j] = (f32x4){0.f, 0.f, 0.f, 0.f};

    int aoff[4], boff[4];
#pragma unroll
    for (int f = 0; f < 4; ++f) {
        const int ra = wm * 64 + f * 16 + li;
        aoff[f] = ra * 32 + ((gg ^ ((ra >> 1) & 3)) * 8);
        const int rb = wn * 64 + f * 16 + li;
        boff[f] = rb * 32 + ((gg ^ ((rb >> 1) & 3)) * 8);
    }

#pragma unroll
    for (int j = 0; j < 2; ++j) {
        const int rl = (w * 2 + j) * 16 + srow;
        const int c  = schk ^ ((rl >> 1) & 3);
        gload16(attn + (size_t)(m0 + rl) * 1024 + c * 8, sA[0] + (w * 2 + j) * 512);
        gload16(Wot + (size_t)(n0 + rl) * 1024 + c * 8,  sB[0] + (w * 2 + j) * 512);
    }
    __syncthreads();

    for (int kt = 0; kt < 32; ++kt) {
        const int cur = kt & 1;
        if (kt < 31) {
            const int k1 = (kt + 1) * 32;
#pragma unroll
            for (int j = 0; j < 2; ++j) {
                const int rl = (w * 2 + j) * 16 + srow;
                const int c  = schk ^ ((rl >> 1) & 3);
                gload16(attn + (size_t)(m0 + rl) * 1024 + k1 + c * 8, sA[cur ^ 1] + (w * 2 + j) * 512);
                gload16(Wot + (size_t)(n0 + rl) * 1024 + k1 + c * 8,  sB[cur ^ 1] + (w * 2 + j) * 512);
            }
        }
        bf16x8 av[4], bw[4];
#pragma unroll
        for (int f = 0; f < 4; ++f) av[f] = *(const bf16x8*)(sA[cur] + aoff[f]);
#pragma unroll
        for (int f = 0; f < 4; ++f) bw[f] = *(const bf16x8*)(sB[cur] + boff[f]);
#pragma unroll
        for (int mf = 0; mf < 4; ++mf)
#pragma unroll
            for (int nf = 0; nf < 4; ++nf)
                acc[mf][nf] = MFMA16x16x32(av[mf], bw[nf], acc[mf][nf]);
        __syncthreads();
    }

#pragma unroll
    for (int nf = 0; nf < 4; ++nf) {
        const int n = n0 + wn * 64 + nf * 16 + li;
        const float bi = bo[n];
#pragma unroll
        for (int mf = 0; mf < 4; ++mf) {
#pragma unroll
            for (int r = 0; r < 4; ++r) {
                const int m = m0 + wm * 64 + mf * 16 + gg * 4 + r;
                out[(size_t)m * 512 + n] = acc[mf][nf][r] + bi;
            }
        }
    }
}

extern "C" void kernel_launch(void* const* d_in, const int* in_sizes, int n_in,
                              void* d_out, int out_size, void* d_ws, size_t ws_size,
                              hipStream_t stream) {
    const float* x  = (const float*)d_in[0];
    const float* Wq = (const float*)d_in[1];
    const float* bq = (const float*)d_in[2];
    const float* Wk = (const float*)d_in[3];
    const float* bk = (const float*)d_in[4];
    const float* Wv = (const float*)d_in[5];
    const float* bv = (const float*)d_in[6];
    const float* Wo = (const float*)d_in[7];
    const float* bo = (const float*)d_in[8];
    float* out = (float*)d_out;

    unsigned short* ws  = (unsigned short*)d_ws;
    unsigned short* xb  = ws;                  // 4096x1024
    unsigned short* Wqt = xb  + 4194304;       // 1024x1024
    unsigned short* Wkt = Wqt + 1048576;
    unsigned short* Wvt = Wkt + 1048576;
    unsigned short* Wot = Wvt + 1048576;       // 512x1024
    unsigned short* Qb  = Wot + 524288;        // [b][h][s][d]
    unsigned short* Kb  = Qb  + 4194304;
    unsigned short* Vb  = Kb  + 4194304;
    unsigned short* Vt  = Vb  + 4194304;       // [b][h][d][s]
    unsigned short* attnb = Vt + 4194304;      // [b][s][h][d]

    cvt_x_kernel<<<dim3(4096), dim3(256), 0, stream>>>(x, xb);
    tr_w_kernel<<<dim3(32, 32), dim3(32, 8), 0, stream>>>(Wq, Wqt, 1024);
    tr_w_kernel<<<dim3(32, 32), dim3(32, 8), 0, stream>>>(Wk, Wkt, 1024);
    tr_w_kernel<<<dim3(32, 32), dim3(32, 8), 0, stream>>>(Wv, Wvt, 1024);
    tr_w_kernel<<<dim3(32, 16), dim3(32, 8), 0, stream>>>(Wo, Wot, 512);
    gemm_qkv_kernel<<<dim3(24, 32), dim3(256), 0, stream>>>(xb, Wqt, Wkt, Wvt,
                                                            bq, bk, bv, Qb, Kb, Vb);
    tr_v_kernel<<<dim3(64, 2, 32), dim3(32, 8), 0, stream>>>(Vb, Vt);
    attn_kernel<<<dim3(16, 32), dim3(256), 0, stream>>>(Qb, Kb, Vt, attnb);
    gemm_out_kernel<<<dim3(4, 32), dim3(256), 0, stream>>>(attnb, Wot, bo, out);
}

// Round 2
// 166.748 us; speedup vs baseline: 1.3300x; 1.3300x over previous
//
#include <hip/hip_runtime.h>

typedef __attribute__((ext_vector_type(8))) __bf16 bf16x8;
typedef __attribute__((ext_vector_type(4))) __bf16 bf16x4;
typedef __attribute__((ext_vector_type(4))) float f32x4;

#define MFMA16x16x32(A, B, C) __builtin_amdgcn_mfma_f32_16x16x32_bf16(A, B, C, 0, 0, 0)

__device__ __forceinline__ unsigned short f2bf(float f) {
    unsigned int u = __float_as_uint(f);
    u += 0x7fffu + ((u >> 16) & 1u);
    return (unsigned short)(u >> 16);
}

__device__ __forceinline__ unsigned cvtpk_bf16(float lo, float hi) {
    unsigned r;
    asm("v_cvt_pk_bf16_f32 %0, %1, %2" : "=v"(r) : "v"(lo), "v"(hi));
    return r;
}

__device__ __forceinline__ void gload16(const void* src, void* lds) {
    __builtin_amdgcn_global_load_lds(
        (const __attribute__((address_space(1))) unsigned int*)src,
        (__attribute__((address_space(3))) unsigned int*)lds,
        16, 0, 0);
}

// ---------------- stage 1: x fp32 -> bf16 ----------------
__global__ __launch_bounds__(256) void cvt_x_kernel(const float* __restrict__ x,
                                                    unsigned short* __restrict__ xb) {
    const int i = (blockIdx.x * 256 + threadIdx.x) * 4;
    const float4 v = *(const float4*)(x + i);
    ushort4 o;
    o.x = f2bf(v.x); o.y = f2bf(v.y); o.z = f2bf(v.z); o.w = f2bf(v.w);
    *(ushort4*)(xb + i) = o;
}

// ---------------- stage 2: W [K][N] fp32 -> Wt [N][K=1024] bf16 ----------------
__global__ __launch_bounds__(256) void tr_w_kernel(const float* __restrict__ W,
                                                   unsigned short* __restrict__ Wt, int N) {
    __shared__ float tile[32][33];
    const int k0 = blockIdx.x * 32;
    const int n0 = blockIdx.y * 32;
    const int tx = threadIdx.x, ty = threadIdx.y;
#pragma unroll
    for (int i = 0; i < 4; ++i)
        tile[ty + 8 * i][tx] = W[(size_t)(k0 + ty + 8 * i) * N + n0 + tx];
    __syncthreads();
#pragma unroll
    for (int i = 0; i < 4; ++i)
        Wt[(size_t)(n0 + ty + 8 * i) * 1024 + k0 + tx] = f2bf(tile[tx][ty + 8 * i]);
}

// ---------------- stage 4: V [bh][s][64] -> Vt [bh][64][s] (bf16) ----------------
__global__ __launch_bounds__(256) void tr_v_kernel(const unsigned short* __restrict__ Vb,
                                                   unsigned short* __restrict__ Vt) {
    __shared__ unsigned short tile[32][33];
    const int bh = blockIdx.z;
    const int s0 = blockIdx.x * 32;
    const int d0 = blockIdx.y * 32;
    const int tx = threadIdx.x, ty = threadIdx.y;
#pragma unroll
    for (int i = 0; i < 4; ++i)
        tile[ty + 8 * i][tx] = Vb[((size_t)bh * 2048 + s0 + ty + 8 * i) * 64 + d0 + tx];
    __syncthreads();
#pragma unroll
    for (int i = 0; i < 4; ++i)
        Vt[((size_t)bh * 64 + d0 + ty + 8 * i) * 2048 + s0 + tx] = tile[tx][ty + 8 * i];
}

// ---------------- stage 3: fused QKV GEMM ----------------
// X [4096][1024] bf16  x  Wt [1024 n][1024 k] bf16  -> Q/K/V [b][h][s][d] bf16 (+bias)
// Q is pre-scaled by log2(e)/sqrt(DH) so attention softmax works in exp2 space.
__global__ __launch_bounds__(256, 2) void gemm_qkv_kernel(
    const unsigned short* __restrict__ xb,
    const unsigned short* __restrict__ Wqt,
    const unsigned short* __restrict__ Wkt,
    const unsigned short* __restrict__ Wvt,
    const float* __restrict__ bq, const float* __restrict__ bk, const float* __restrict__ bv,
    unsigned short* __restrict__ Qb, unsigned short* __restrict__ Kb, unsigned short* __restrict__ Vb)
{
    __shared__ unsigned short sA[2][128 * 32];
    __shared__ unsigned short sB[2][128 * 32];

    const int tid  = threadIdx.x;
    const int lane = tid & 63;
    const int w    = tid >> 6;
    const int wm   = w >> 1, wn = w & 1;
    const int li   = lane & 15, gg = lane >> 4;
    const int m0   = blockIdx.y * 128;
    const int which = blockIdx.x >> 3;
    const int nloc0 = (blockIdx.x & 7) * 128;

    const unsigned short* Wt = (which == 0) ? Wqt : ((which == 1) ? Wkt : Wvt);
    const float* bias        = (which == 0) ? bq  : ((which == 1) ? bk  : bv);
    unsigned short* dst      = (which == 0) ? Qb  : ((which == 1) ? Kb  : Vb);
    const float osc          = (which == 0) ? 0.18033688011112042f : 1.0f; // log2(e)/8

    const int srow = lane >> 2;   // row within 16-row chunk
    const int schk = lane & 3;    // 16B chunk within 64B row

    f32x4 acc[4][4];
#pragma unroll
    for (int i = 0; i < 4; ++i)
#pragma unroll
        for (int j = 0; j < 4; ++j)
            acc[i][j] = (f32x4){0.f, 0.f, 0.f, 0.f};

    int aoff[4], boff[4];
#pragma unroll
    for (int f = 0; f < 4; ++f) {
        const int ra = wm * 64 + f * 16 + li;
        aoff[f] = ra * 32 + ((gg ^ ((ra >> 1) & 3)) * 8);
        const int rb = wn * 64 + f * 16 + li;
        boff[f] = rb * 32 + ((gg ^ ((rb >> 1) & 3)) * 8);
    }

#pragma unroll
    for (int j = 0; j < 2; ++j) {
        const int rl = (w * 2 + j) * 16 + srow;
        const int c  = schk ^ ((rl >> 1) & 3);
        gload16(xb + (size_t)(m0 + rl) * 1024 + c * 8,   sA[0] + (w * 2 + j) * 512);
        gload16(Wt + (size_t)(nloc0 + rl) * 1024 + c * 8, sB[0] + (w * 2 + j) * 512);
    }
    __syncthreads();

    for (int kt = 0; kt < 32; ++kt) {
        const int cur = kt & 1;
        if (kt < 31) {
            const int k1 = (kt + 1) * 32;
#pragma unroll
            for (int j = 0; j < 2; ++j) {
                const int rl = (w * 2 + j) * 16 + srow;
                const int c  = schk ^ ((rl >> 1) & 3);
                gload16(xb + (size_t)(m0 + rl) * 1024 + k1 + c * 8,   sA[cur ^ 1] + (w * 2 + j) * 512);
                gload16(Wt + (size_t)(nloc0 + rl) * 1024 + k1 + c * 8, sB[cur ^ 1] + (w * 2 + j) * 512);
            }
        }
        bf16x8 av[4], bw[4];
#pragma unroll
        for (int f = 0; f < 4; ++f) av[f] = *(const bf16x8*)(sA[cur] + aoff[f]);
#pragma unroll
        for (int f = 0; f < 4; ++f) bw[f] = *(const bf16x8*)(sB[cur] + boff[f]);
#pragma unroll
        for (int mf = 0; mf < 4; ++mf)
#pragma unroll
            for (int nf = 0; nf < 4; ++nf)
                acc[mf][nf] = MFMA16x16x32(av[mf], bw[nf], acc[mf][nf]);
        __syncthreads();
    }

#pragma unroll
    for (int nf = 0; nf < 4; ++nf) {
        const int nl = nloc0 + wn * 64 + nf * 16 + li;
        const float bi = bias[nl];
        const int h = nl >> 6, d = nl & 63;
#pragma unroll
        for (int mf = 0; mf < 4; ++mf) {
#pragma unroll
            for (int r = 0; r < 4; ++r) {
                const int m = m0 + wm * 64 + mf * 16 + gg * 4 + r;
                const int b = m >> 11, s = m & 2047;
                dst[(((size_t)(b * 16 + h)) * 2048 + s) * 64 + d] = f2bf((acc[mf][nf][r] + bi) * osc);
            }
        }
    }
}

// ---------------- stage 5: flash attention (swapped-QK^T, in-register softmax) ----
// grid (16 q-tiles, 32 bh); 4 waves x 32 q-rows; KV tiles of 64.
// S^T = mfma(K,Q): lane holds q = mq*16 + (lane&15), k = nf*16 + gg*4 + r (in-reg).
__global__ __launch_bounds__(256, 2) void attn_kernel(
    const unsigned short* __restrict__ Qb,
    const unsigned short* __restrict__ Kb,
    const unsigned short* __restrict__ Vt,
    unsigned short* __restrict__ Ob)
{
    __shared__ unsigned short sK[2][64 * 64];
    __shared__ unsigned short sV[2][64 * 64];
    __shared__ unsigned short sP[4][32 * 64];   // per-wave P tile [qloc][k], XOR-swizzled

    const int tid  = threadIdx.x;
    const int lane = tid & 63;
    const int w    = tid >> 6;
    const int li   = lane & 15, gg = lane >> 4;
    const int bh   = blockIdx.y;
    const int q0   = blockIdx.x * 128 + w * 32;

    const int srow8 = lane >> 3;
    const int sc8   = lane & 7;
    char* const sPw = (char*)sP[w];
    const int swz = (li & 7) << 4;

    // Q fragments (already scaled by log2(e)/8) held in registers
    bf16x8 qf[2][2];
#pragma unroll
    for (int mq = 0; mq < 2; ++mq)
#pragma unroll
        for (int kk = 0; kk < 2; ++kk) {
            const int q = q0 + mq * 16 + li;
            const int d = kk * 32 + gg * 8;
            qf[mq][kk] = *(const bf16x8*)(Qb + ((size_t)bh * 2048 + q) * 64 + d);
        }

    f32x4 acc[2][4];
    float m_s[2], l_s[2];
#pragma unroll
    for (int mf = 0; mf < 2; ++mf) {
#pragma unroll
        for (int df = 0; df < 4; ++df) acc[mf][df] = (f32x4){0.f, 0.f, 0.f, 0.f};
        m_s[mf] = -1e30f; l_s[mf] = 0.f;
    }

#pragma unroll
    for (int j = 0; j < 2; ++j) {
        const int rl = (w * 2 + j) * 8 + srow8;
        const int c  = sc8 ^ (rl & 7);
        gload16(Kb + ((size_t)bh * 2048 + rl) * 64 + c * 8, sK[0] + (w * 2 + j) * 512);
        gload16(Vt + ((size_t)bh * 64 + rl) * 2048 + c * 8, sV[0] + (w * 2 + j) * 512);
    }
    __syncthreads();

    for (int t = 0; t < 32; ++t) {
        const int cur = t & 1;
        if (t < 31) {
#pragma unroll
            for (int j = 0; j < 2; ++j) {
                const int rl = (w * 2 + j) * 8 + srow8;
                const int c  = sc8 ^ (rl & 7);
                gload16(Kb + ((size_t)bh * 2048 + (t + 1) * 64 + rl) * 64 + c * 8,
                        sK[cur ^ 1] + (w * 2 + j) * 512);
                gload16(Vt + ((size_t)bh * 64 + rl) * 2048 + (t + 1) * 64 + c * 8,
                        sV[cur ^ 1] + (w * 2 + j) * 512);
            }
        }

        // ---- S^T = mfma(K, Q): st[mq][nf], q = mq*16+li, k = nf*16+gg*4+r ----
        bf16x8 kf[4][2];
#pragma unroll
        for (int nf = 0; nf < 4; ++nf)
#pragma unroll
            for (int kk = 0; kk < 2; ++kk) {
                const int n = nf * 16 + li;
                const int ch = kk * 4 + gg;
                kf[nf][kk] = *(const bf16x8*)(sK[cur] + n * 64 + ((ch ^ (n & 7)) * 8));
            }
        f32x4 st[2][4];
#pragma unroll
        for (int mq = 0; mq < 2; ++mq)
#pragma unroll
            for (int nf = 0; nf < 4; ++nf) {
                st[mq][nf] = (f32x4){0.f, 0.f, 0.f, 0.f};
                st[mq][nf] = MFMA16x16x32(kf[nf][0], qf[mq][0], st[mq][nf]);
                st[mq][nf] = MFMA16x16x32(kf[nf][1], qf[mq][1], st[mq][nf]);
            }

        // ---- online softmax, fully in-register (k is in-lane) ----
        float alpha_q[2];
#pragma unroll
        for (int mq = 0; mq < 2; ++mq) {
            // 16-value in-lane max + 2 cross-gg shuffles
            float t0 = fmaxf(fmaxf(st[mq][0][0], st[mq][0][1]), fmaxf(st[mq][0][2], st[mq][0][3]));
            float t1 = fmaxf(fmaxf(st[mq][1][0], st[mq][1][1]), fmaxf(st[mq][1][2], st[mq][1][3]));
            float t2 = fmaxf(fmaxf(st[mq][2][0], st[mq][2][1]), fmaxf(st[mq][2][2], st[mq][2][3]));
            float t3 = fmaxf(fmaxf(st[mq][3][0], st[mq][3][1]), fmaxf(st[mq][3][2], st[mq][3][3]));
            float tm = fmaxf(fmaxf(t0, t1), fmaxf(t2, t3));
            tm = fmaxf(tm, __shfl_xor(tm, 16, 64));
            tm = fmaxf(tm, __shfl_xor(tm, 32, 64));
            const float mnew = fmaxf(m_s[mq], tm);
            alpha_q[mq] = exp2f(m_s[mq] - mnew);
            m_s[mq] = mnew;
            float rs = 0.f;
#pragma unroll
            for (int nf = 0; nf < 4; ++nf)
#pragma unroll
                for (int r = 0; r < 4; ++r) {
                    const float p = exp2f(st[mq][nf][r] - mnew);
                    st[mq][nf][r] = p;
                    rs += p;
                }
            rs += __shfl_xor(rs, 16, 64);
            rs += __shfl_xor(rs, 32, 64);
            l_s[mq] = l_s[mq] * alpha_q[mq] + rs;

            // pack P (k-adjacent in r) and store 8B per nf, swizzled
#pragma unroll
            for (int nf = 0; nf < 4; ++nf) {
                uint2 pv;
                pv.x = cvtpk_bf16(st[mq][nf][0], st[mq][nf][1]);
                pv.y = cvtpk_bf16(st[mq][nf][2], st[mq][nf][3]);
                const int byte = ((mq * 16 + li) * 128 + nf * 32 + gg * 8) ^ swz;
                *(uint2*)(sPw + byte) = pv;
            }
        }

        // ---- broadcast alpha to accumulator rows, rescale ----
        float al[2][4];
#pragma unroll
        for (int mf = 0; mf < 2; ++mf)
#pragma unroll
            for (int r = 0; r < 4; ++r)
                al[mf][r] = __shfl(alpha_q[mf], gg * 4 + r, 64);
#pragma unroll
        for (int mf = 0; mf < 2; ++mf)
#pragma unroll
            for (int df = 0; df < 4; ++df)
#pragma unroll
                for (int r = 0; r < 4; ++r)
                    acc[mf][df][r] *= al[mf][r];

        // ---- PV: O[q][d] += P[q][k] Vt[d][k] ----
        bf16x8 pf[2][2];
#pragma unroll
        for (int mf = 0; mf < 2; ++mf)
#pragma unroll
            for (int kk = 0; kk < 2; ++kk) {
                const int byte = ((mf * 16 + li) * 128 + kk * 64 + gg * 16) ^ swz;
                pf[mf][kk] = *(const bf16x8*)(sPw + byte);
            }
        bf16x8 vf[4][2];
#pragma unroll
        for (int df = 0; df < 4; ++df)
#pragma unroll
            for (int kk = 0; kk < 2; ++kk) {
                const int n = df * 16 + li;
                const int ch = kk * 4 + gg;
                vf[df][kk] = *(const bf16x8*)(sV[cur] + n * 64 + ((ch ^ (n & 7)) * 8));
            }
#pragma unroll
        for (int mf = 0; mf < 2; ++mf)
#pragma unroll
            for (int df = 0; df < 4; ++df) {
                acc[mf][df] = MFMA16x16x32(pf[mf][0], vf[df][0], acc[mf][df]);
                acc[mf][df] = MFMA16x16x32(pf[mf][1], vf[df][1], acc[mf][df]);
            }
        __syncthreads();
    }

    // epilogue: O = acc / l  -> attn buffer [b][s][h][d] (bf16)
    const int b = bh >> 4, h = bh & 15;
#pragma unroll
    for (int mf = 0; mf < 2; ++mf)
#pragma unroll
        for (int r = 0; r < 4; ++r) {
            const float lbc = __shfl(l_s[mf], gg * 4 + r, 64);
            const float rl = 1.0f / lbc;
            const int q = q0 + mf * 16 + gg * 4 + r;
#pragma unroll
            for (int df = 0; df < 4; ++df) {
                const int d = df * 16 + li;
                Ob[(((size_t)b * 2048 + q) * 16 + h) * 64 + d] = f2bf(acc[mf][df][r] * rl);
            }
        }
}

// ---------------- stage 6: output projection ----------------
__global__ __launch_bounds__(256, 2) void gemm_out_kernel(
    const unsigned short* __restrict__ attn,
    const unsigned short* __restrict__ Wot,
    const float* __restrict__ bo,
    float* __restrict__ out)
{
    __shared__ unsigned short sA[2][128 * 32];
    __shared__ unsigned short sB[2][128 * 32];

    const int tid  = threadIdx.x;
    const int lane = tid & 63;
    const int w    = tid >> 6;
    const int wm   = w >> 1, wn = w & 1;
    const int li   = lane & 15, gg = lane >> 4;
    const int m0   = blockIdx.y * 128;
    const int n0   = blockIdx.x * 128;

    const int srow = lane >> 2;
    const int schk = lane & 3;

    f32x4 acc[4][4];
#pragma unroll
    for (int i = 0; i < 4; ++i)
#pragma unroll
        for (int j = 0; j < 4; ++j)
            acc[i][j] = (f32x4){0.f, 0.f, 0.f, 0.f};

    int aoff[4], boff[4];
#pragma unroll
    for (int f = 0; f < 4; ++f) {
        const int ra = wm * 64 + f * 16 + li;
        aoff[f] = ra * 32 + ((gg ^ ((ra >> 1) & 3)) * 8);
        const int rb = wn * 64 + f * 16 + li;
        boff[f] = rb * 32 + ((gg ^ ((rb >> 1) & 3)) * 8);
    }

#pragma unroll
    for (int j = 0; j < 2; ++j) {
        const int rl = (w * 2 + j) * 16 + srow;
        const int c  = schk ^ ((rl >> 1) & 3);
        gload16(attn + (size_t)(m0 + rl) * 1024 + c * 8, sA[0] + (w * 2 + j) * 512);
        gload16(Wot + (size_t)(n0 + rl) * 1024 + c * 8,  sB[0] + (w * 2 + j) * 512);
    }
    __syncthreads();

    for (int kt = 0; kt < 32; ++kt) {
        const int cur = kt & 1;
        if (kt < 31) {
            const int k1 = (kt + 1) * 32;
#pragma unroll
            for (int j = 0; j < 2; ++j) {
                const int rl = (w * 2 + j) * 16 + srow;
                const int c  = schk ^ ((rl >> 1) & 3);
                gload16(attn + (size_t)(m0 + rl) * 1024 + k1 + c * 8, sA[cur ^ 1] + (w * 2 + j) * 512);
                gload16(Wot + (size_t)(n0 + rl) * 1024 + k1 + c * 8,  sB[cur ^ 1] + (w * 2 + j) * 512);
            }
        }
        bf16x8 av[4], bw[4];
#pragma unroll
        for (int f = 0; f < 4; ++f) av[f] = *(const bf16x8*)(sA[cur] + aoff[f]);
#pragma unroll
        for (int f = 0; f < 4; ++f) bw[f] = *(const bf16x8*)(sB[cur] + boff[f]);
#pragma unroll
        for (int mf = 0; mf < 4; ++mf)
#pragma unroll
            for (int nf = 0; nf < 4; ++nf)
                acc[mf][nf] = MFMA16x16x32(av[mf], bw[nf], acc[mf][nf]);
        __syncthreads();
    }

#pragma unroll
    for (int nf = 0; nf < 4; ++nf) {
        const int n = n0 + wn * 64 + nf * 16 + li;
        const float bi = bo[n];
#pragma unroll
        for (int mf = 0; mf < 4; ++mf) {
#pragma unroll
            for (int r = 0; r < 4; ++r) {
                const int m = m0 + wm * 64 + mf * 16 + gg * 4 + r;
                out[(size_t)m * 512 + n] = acc[mf][nf][r] + bi;
            }
        }
    }
}

extern "C" void kernel_launch(void* const* d_in, const int* in_sizes, int n_in,
                              void* d_out, int out_size, void* d_ws, size_t ws_size,
                              hipStream_t stream) {
    const float* x  = (const float*)d_in[0];
    const float* Wq = (const float*)d_in[1];
    const float* bq = (const float*)d_in[2];
    const float* Wk = (const float*)d_in[3];
    const float* bk = (const float*)d_in[4];
    const float* Wv = (const float*)d_in[5];
    const float* bv = (const float*)d_in[6];
    const float* Wo = (const float*)d_in[7];
    const float* bo = (const float*)d_in[8];
    float* out = (float*)d_out;

    unsigned short* ws  = (unsigned short*)d_ws;
    unsigned short* xb  = ws;                  // 4096x1024
    unsigned short* Wqt = xb  + 4194304;       // 1024x1024
    unsigned short* Wkt = Wqt + 1048576;
    unsigned short* Wvt = Wkt + 1048576;
    unsigned short* Wot = Wvt + 1048576;       // 512x1024
    unsigned short* Qb  = Wot + 524288;        // [b][h][s][d]
    unsigned short* Kb  = Qb  + 4194304;
    unsigned short* Vb  = Kb  + 4194304;
    unsigned short* Vt  = Vb  + 4194304;       // [b][h][d][s]
    unsigned short* attnb = Vt + 4194304;      // [b][s][h][d]

    cvt_x_kernel<<<dim3(4096), dim3(256), 0, stream>>>(x, xb);
    tr_w_kernel<<<dim3(32, 32), dim3(32, 8), 0, stream>>>(Wq, Wqt, 1024);
    tr_w_kernel<<<dim3(32, 32), dim3(32, 8), 0, stream>>>(Wk, Wkt, 1024);
    tr_w_kernel<<<dim3(32, 32), dim3(32, 8), 0, stream>>>(Wv, Wvt, 1024);
    tr_w_kernel<<<dim3(32, 16), dim3(32, 8), 0, stream>>>(Wo, Wot, 512);
    gemm_qkv_kernel<<<dim3(24, 32), dim3(256), 0, stream>>>(xb, Wqt, Wkt, Wvt,
                                                            bq, bk, bv, Qb, Kb, Vb);
    tr_v_kernel<<<dim3(64, 2, 32), dim3(32, 8), 0, stream>>>(Vb, Vt);
    attn_kernel<<<dim3(16, 32), dim3(256), 0, stream>>>(Qb, Kb, Vt, attnb);
    gemm_out_kernel<<<dim3(4, 32), dim3(256), 0, stream>>>(attnb, Wot, bo, out);
}

// Round 3
// 148.043 us; speedup vs baseline: 1.4981x; 1.1263x over previous
//
#include <hip/hip_runtime.h>

typedef __attribute__((ext_vector_type(8))) __bf16 bf16x8;
typedef __attribute__((ext_vector_type(4))) __bf16 bf16x4;
typedef __attribute__((ext_vector_type(4))) float f32x4;

#define MFMA16x16x32(A, B, C) __builtin_amdgcn_mfma_f32_16x16x32_bf16(A, B, C, 0, 0, 0)

__device__ __forceinline__ unsigned short f2bf(float f) {
    unsigned int u = __float_as_uint(f);
    u += 0x7fffu + ((u >> 16) & 1u);
    return (unsigned short)(u >> 16);
}

__device__ __forceinline__ unsigned cvtpk_bf16(float lo, float hi) {
    unsigned r;
    asm("v_cvt_pk_bf16_f32 %0, %1, %2" : "=v"(r) : "v"(lo), "v"(hi));
    return r;
}

__device__ __forceinline__ void gload16(const void* src, void* lds) {
    __builtin_amdgcn_global_load_lds(
        (const __attribute__((address_space(1))) unsigned int*)src,
        (__attribute__((address_space(3))) unsigned int*)lds,
        16, 0, 0);
}

// ---------------- stage 1: x fp32 -> bf16 ----------------
__global__ __launch_bounds__(256) void cvt_x_kernel(const float* __restrict__ x,
                                                    unsigned short* __restrict__ xb) {
    const int i = (blockIdx.x * 256 + threadIdx.x) * 4;
    const float4 v = *(const float4*)(x + i);
    ushort4 o;
    o.x = f2bf(v.x); o.y = f2bf(v.y); o.z = f2bf(v.z); o.w = f2bf(v.w);
    *(ushort4*)(xb + i) = o;
}

// ---------------- stage 2: W [K][N] fp32 -> Wt [N][K=1024] bf16 ----------------
__global__ __launch_bounds__(256) void tr_w_kernel(const float* __restrict__ W,
                                                   unsigned short* __restrict__ Wt, int N) {
    __shared__ float tile[32][33];
    const int k0 = blockIdx.x * 32;
    const int n0 = blockIdx.y * 32;
    const int tx = threadIdx.x, ty = threadIdx.y;
#pragma unroll
    for (int i = 0; i < 4; ++i)
        tile[ty + 8 * i][tx] = W[(size_t)(k0 + ty + 8 * i) * N + n0 + tx];
    __syncthreads();
#pragma unroll
    for (int i = 0; i < 4; ++i)
        Wt[(size_t)(n0 + ty + 8 * i) * 1024 + k0 + tx] = f2bf(tile[tx][ty + 8 * i]);
}

// ---------------- stage 4: V [bh][s][64] -> Vt [bh][64][s] (bf16) ----------------
__global__ __launch_bounds__(256) void tr_v_kernel(const unsigned short* __restrict__ Vb,
                                                   unsigned short* __restrict__ Vt) {
    __shared__ unsigned short tile[32][33];
    const int bh = blockIdx.z;
    const int s0 = blockIdx.x * 32;
    const int d0 = blockIdx.y * 32;
    const int tx = threadIdx.x, ty = threadIdx.y;
#pragma unroll
    for (int i = 0; i < 4; ++i)
        tile[ty + 8 * i][tx] = Vb[((size_t)bh * 2048 + s0 + ty + 8 * i) * 64 + d0 + tx];
    __syncthreads();
#pragma unroll
    for (int i = 0; i < 4; ++i)
        Vt[((size_t)bh * 64 + d0 + ty + 8 * i) * 2048 + s0 + tx] = tile[tx][ty + 8 * i];
}

// ---------------- stage 3: fused QKV GEMM ----------------
// X [4096][1024] bf16  x  Wt [1024 n][1024 k] bf16  -> Q/K/V [b][h][s][d] bf16 (+bias)
// Q is pre-scaled by log2(e)/sqrt(DH) so attention softmax works in exp2 space.
__global__ __launch_bounds__(256, 2) void gemm_qkv_kernel(
    const unsigned short* __restrict__ xb,
    const unsigned short* __restrict__ Wqt,
    const unsigned short* __restrict__ Wkt,
    const unsigned short* __restrict__ Wvt,
    const float* __restrict__ bq, const float* __restrict__ bk, const float* __restrict__ bv,
    unsigned short* __restrict__ Qb, unsigned short* __restrict__ Kb, unsigned short* __restrict__ Vb)
{
    __shared__ unsigned short sA[2][128 * 32];
    __shared__ unsigned short sB[2][128 * 32];

    const int tid  = threadIdx.x;
    const int lane = tid & 63;
    const int w    = tid >> 6;
    const int wm   = w >> 1, wn = w & 1;
    const int li   = lane & 15, gg = lane >> 4;
    const int m0   = blockIdx.y * 128;
    const int which = blockIdx.x >> 3;
    const int nloc0 = (blockIdx.x & 7) * 128;

    const unsigned short* Wt = (which == 0) ? Wqt : ((which == 1) ? Wkt : Wvt);
    const float* bias        = (which == 0) ? bq  : ((which == 1) ? bk  : bv);
    unsigned short* dst      = (which == 0) ? Qb  : ((which == 1) ? Kb  : Vb);
    const float osc          = (which == 0) ? 0.18033688011112042f : 1.0f; // log2(e)/8

    const int srow = lane >> 2;   // row within 16-row chunk
    const int schk = lane & 3;    // 16B chunk within 64B row

    f32x4 acc[4][4];
#pragma unroll
    for (int i = 0; i < 4; ++i)
#pragma unroll
        for (int j = 0; j < 4; ++j)
            acc[i][j] = (f32x4){0.f, 0.f, 0.f, 0.f};

    int aoff[4], boff[4];
#pragma unroll
    for (int f = 0; f < 4; ++f) {
        const int ra = wm * 64 + f * 16 + li;
        aoff[f] = ra * 32 + ((gg ^ ((ra >> 1) & 3)) * 8);
        const int rb = wn * 64 + f * 16 + li;
        boff[f] = rb * 32 + ((gg ^ ((rb >> 1) & 3)) * 8);
    }

#pragma unroll
    for (int j = 0; j < 2; ++j) {
        const int rl = (w * 2 + j) * 16 + srow;
        const int c  = schk ^ ((rl >> 1) & 3);
        gload16(xb + (size_t)(m0 + rl) * 1024 + c * 8,   sA[0] + (w * 2 + j) * 512);
        gload16(Wt + (size_t)(nloc0 + rl) * 1024 + c * 8, sB[0] + (w * 2 + j) * 512);
    }
    __syncthreads();

    for (int kt = 0; kt < 32; ++kt) {
        const int cur = kt & 1;
        if (kt < 31) {
            const int k1 = (kt + 1) * 32;
#pragma unroll
            for (int j = 0; j < 2; ++j) {
                const int rl = (w * 2 + j) * 16 + srow;
                const int c  = schk ^ ((rl >> 1) & 3);
                gload16(xb + (size_t)(m0 + rl) * 1024 + k1 + c * 8,   sA[cur ^ 1] + (w * 2 + j) * 512);
                gload16(Wt + (size_t)(nloc0 + rl) * 1024 + k1 + c * 8, sB[cur ^ 1] + (w * 2 + j) * 512);
            }
        }
        bf16x8 av[4], bw[4];
#pragma unroll
        for (int f = 0; f < 4; ++f) av[f] = *(const bf16x8*)(sA[cur] + aoff[f]);
#pragma unroll
        for (int f = 0; f < 4; ++f) bw[f] = *(const bf16x8*)(sB[cur] + boff[f]);
#pragma unroll
        for (int mf = 0; mf < 4; ++mf)
#pragma unroll
            for (int nf = 0; nf < 4; ++nf)
                acc[mf][nf] = MFMA16x16x32(av[mf], bw[nf], acc[mf][nf]);
        __syncthreads();
    }

#pragma unroll
    for (int nf = 0; nf < 4; ++nf) {
        const int nl = nloc0 + wn * 64 + nf * 16 + li;
        const float bi = bias[nl];
        const int h = nl >> 6, d = nl & 63;
#pragma unroll
        for (int mf = 0; mf < 4; ++mf) {
#pragma unroll
            for (int r = 0; r < 4; ++r) {
                const int m = m0 + wm * 64 + mf * 16 + gg * 4 + r;
                const int b = m >> 11, s = m & 2047;
                dst[(((size_t)(b * 16 + h)) * 2048 + s) * 64 + d] = f2bf((acc[mf][nf][r] + bi) * osc);
            }
        }
    }
}

// ---------------- stage 5: flash attention v3 ----------------
// 512 threads = 8 waves, 16 q-rows per wave (block = 128 q); grid (16, 32).
// 2 blocks/CU -> 16 waves/CU (4/SIMD). Swapped QK^T, in-register softmax,
// defer-max (THR=8 in log2 space) skips rescale on most tiles.
__global__ __launch_bounds__(512, 4) void attn_kernel(
    const unsigned short* __restrict__ Qb,
    const unsigned short* __restrict__ Kb,
    const unsigned short* __restrict__ Vt,
    unsigned short* __restrict__ Ob)
{
    __shared__ unsigned short sK[2][64 * 64];
    __shared__ unsigned short sV[2][64 * 64];
    __shared__ unsigned short sP[8][16 * 64];   // per-wave P tile [16 q][64 k], swizzled

    const int tid  = threadIdx.x;
    const int lane = tid & 63;
    const int w    = tid >> 6;        // 0..7
    const int li   = lane & 15, gg = lane >> 4;
    const int bh   = blockIdx.y;
    const int q0   = blockIdx.x * 128 + w * 16;

    // staging: thread stages one 16B K chunk + one 16B V chunk (tile 64x64 each)
    const int slot = w * 64 + lane;          // 0..511
    const int srow = slot >> 3;              // 0..63
    const int schk = (slot & 7) ^ (srow & 7);

    char* const sPw = (char*)sP[w];
    const int swz = (li & 7) << 4;

    // Q fragments (pre-scaled by log2(e)/8) in registers for whole kernel
    bf16x8 qf[2];
#pragma unroll
    for (int kk = 0; kk < 2; ++kk) {
        const int q = q0 + li;
        const int d = kk * 32 + gg * 8;
        qf[kk] = *(const bf16x8*)(Qb + ((size_t)bh * 2048 + q) * 64 + d);
    }

    f32x4 acc[4];
#pragma unroll
    for (int df = 0; df < 4; ++df) acc[df] = (f32x4){0.f, 0.f, 0.f, 0.f};
    float m_s = -1e30f, l_s = 0.f;

    gload16(Kb + ((size_t)bh * 2048 + srow) * 64 + schk * 8, sK[0] + slot * 8);
    gload16(Vt + ((size_t)bh * 64 + srow) * 2048 + schk * 8, sV[0] + slot * 8);
    __syncthreads();

    for (int t = 0; t < 32; ++t) {
        const int cur = t & 1;
        if (t < 31) {
            gload16(Kb + ((size_t)bh * 2048 + (t + 1) * 64 + srow) * 64 + schk * 8,
                    sK[cur ^ 1] + slot * 8);
            gload16(Vt + ((size_t)bh * 64 + srow) * 2048 + (t + 1) * 64 + schk * 8,
                    sV[cur ^ 1] + slot * 8);
        }

        // ---- S^T = mfma(K, Q): st[nf], q = q0+li, k = nf*16 + gg*4 + r ----
        bf16x8 kf[4][2];
#pragma unroll
        for (int nf = 0; nf < 4; ++nf)
#pragma unroll
            for (int kk = 0; kk < 2; ++kk) {
                const int n = nf * 16 + li;
                const int ch = kk * 4 + gg;
                kf[nf][kk] = *(const bf16x8*)(sK[cur] + n * 64 + ((ch ^ (n & 7)) * 8));
            }
        f32x4 st[4];
#pragma unroll
        for (int nf = 0; nf < 4; ++nf) {
            st[nf] = (f32x4){0.f, 0.f, 0.f, 0.f};
            st[nf] = MFMA16x16x32(kf[nf][0], qf[0], st[nf]);
            st[nf] = MFMA16x16x32(kf[nf][1], qf[1], st[nf]);
        }

        // ---- online softmax with defer-max ----
        float t0 = fmaxf(fmaxf(st[0][0], st[0][1]), fmaxf(st[0][2], st[0][3]));
        float t1 = fmaxf(fmaxf(st[1][0], st[1][1]), fmaxf(st[1][2], st[1][3]));
        float t2 = fmaxf(fmaxf(st[2][0], st[2][1]), fmaxf(st[2][2], st[2][3]));
        float t3 = fmaxf(fmaxf(st[3][0], st[3][1]), fmaxf(st[3][2], st[3][3]));
        float tm = fmaxf(fmaxf(t0, t1), fmaxf(t2, t3));
        tm = fmaxf(tm, __shfl_xor(tm, 16, 64));
        tm = fmaxf(tm, __shfl_xor(tm, 32, 64));

        if (!__all(tm - m_s <= 8.0f)) {
            const float mnew = fmaxf(m_s, tm);
            const float alpha = exp2f(m_s - mnew);
            m_s = mnew;
            l_s *= alpha;
            float al[4];
#pragma unroll
            for (int r = 0; r < 4; ++r) al[r] = __shfl(alpha, gg * 4 + r, 64);
#pragma unroll
            for (int df = 0; df < 4; ++df)
#pragma unroll
                for (int r = 0; r < 4; ++r)
                    acc[df][r] *= al[r];
        }

        float rs = 0.f;
#pragma unroll
        for (int nf = 0; nf < 4; ++nf)
#pragma unroll
            for (int r = 0; r < 4; ++r) {
                const float p = exp2f(st[nf][r] - m_s);
                st[nf][r] = p;
                rs += p;
            }
        rs += __shfl_xor(rs, 16, 64);
        rs += __shfl_xor(rs, 32, 64);
        l_s += rs;

        // pack P (k-adjacent in r) and store 8B per nf, swizzled, wave-private
#pragma unroll
        for (int nf = 0; nf < 4; ++nf) {
            uint2 pv;
            pv.x = cvtpk_bf16(st[nf][0], st[nf][1]);
            pv.y = cvtpk_bf16(st[nf][2], st[nf][3]);
            const int byte = (li * 128 + nf * 32 + gg * 8) ^ swz;
            *(uint2*)(sPw + byte) = pv;
        }

        // ---- PV: O[q][d] += P[q][k] Vt[d][k] ----
        bf16x8 pf[2];
#pragma unroll
        for (int kk = 0; kk < 2; ++kk) {
            const int byte = (li * 128 + kk * 64 + gg * 16) ^ swz;
            pf[kk] = *(const bf16x8*)(sPw + byte);
        }
        bf16x8 vf[4][2];
#pragma unroll
        for (int df = 0; df < 4; ++df)
#pragma unroll
            for (int kk = 0; kk < 2; ++kk) {
                const int n = df * 16 + li;
                const int ch = kk * 4 + gg;
                vf[df][kk] = *(const bf16x8*)(sV[cur] + n * 64 + ((ch ^ (n & 7)) * 8));
            }
#pragma unroll
        for (int df = 0; df < 4; ++df) {
            acc[df] = MFMA16x16x32(pf[0], vf[df][0], acc[df]);
            acc[df] = MFMA16x16x32(pf[1], vf[df][1], acc[df]);
        }
        __syncthreads();
    }

    // epilogue: O = acc / l  -> attn buffer [b][s][h][d] (bf16)
    const int b = bh >> 4, h = bh & 15;
#pragma unroll
    for (int r = 0; r < 4; ++r) {
        const float lbc = __shfl(l_s, gg * 4 + r, 64);
        const float rl = 1.0f / lbc;
        const int q = q0 + gg * 4 + r;
#pragma unroll
        for (int df = 0; df < 4; ++df) {
            const int d = df * 16 + li;
            Ob[(((size_t)b * 2048 + q) * 16 + h) * 64 + d] = f2bf(acc[df][r] * rl);
        }
    }
}

// ---------------- stage 6: output projection ----------------
__global__ __launch_bounds__(256, 2) void gemm_out_kernel(
    const unsigned short* __restrict__ attn,
    const unsigned short* __restrict__ Wot,
    const float* __restrict__ bo,
    float* __restrict__ out)
{
    __shared__ unsigned short sA[2][128 * 32];
    __shared__ unsigned short sB[2][128 * 32];

    const int tid  = threadIdx.x;
    const int lane = tid & 63;
    const int w    = tid >> 6;
    const int wm   = w >> 1, wn = w & 1;
    const int li   = lane & 15, gg = lane >> 4;
    const int m0   = blockIdx.y * 128;
    const int n0   = blockIdx.x * 128;

    const int srow = lane >> 2;
    const int schk = lane & 3;

    f32x4 acc[4][4];
#pragma unroll
    for (int i = 0; i < 4; ++i)
#pragma unroll
        for (int j = 0; j < 4; ++j)
            acc[i][j] = (f32x4){0.f, 0.f, 0.f, 0.f};

    int aoff[4], boff[4];
#pragma unroll
    for (int f = 0; f < 4; ++f) {
        const int ra = wm * 64 + f * 16 + li;
        aoff[f] = ra * 32 + ((gg ^ ((ra >> 1) & 3)) * 8);
        const int rb = wn * 64 + f * 16 + li;
        boff[f] = rb * 32 + ((gg ^ ((rb >> 1) & 3)) * 8);
    }

#pragma unroll
    for (int j = 0; j < 2; ++j) {
        const int rl = (w * 2 + j) * 16 + srow;
        const int c  = schk ^ ((rl >> 1) & 3);
        gload16(attn + (size_t)(m0 + rl) * 1024 + c * 8, sA[0] + (w * 2 + j) * 512);
        gload16(Wot + (size_t)(n0 + rl) * 1024 + c * 8,  sB[0] + (w * 2 + j) * 512);
    }
    __syncthreads();

    for (int kt = 0; kt < 32; ++kt) {
        const int cur = kt & 1;
        if (kt < 31) {
            const int k1 = (kt + 1) * 32;
#pragma unroll
            for (int j = 0; j < 2; ++j) {
                const int rl = (w * 2 + j) * 16 + srow;
                const int c  = schk ^ ((rl >> 1) & 3);
                gload16(attn + (size_t)(m0 + rl) * 1024 + k1 + c * 8, sA[cur ^ 1] + (w * 2 + j) * 512);
                gload16(Wot + (size_t)(n0 + rl) * 1024 + k1 + c * 8,  sB[cur ^ 1] + (w * 2 + j) * 512);
            }
        }
        bf16x8 av[4], bw[4];
#pragma unroll
        for (int f = 0; f < 4; ++f) av[f] = *(const bf16x8*)(sA[cur] + aoff[f]);
#pragma unroll
        for (int f = 0; f < 4; ++f) bw[f] = *(const bf16x8*)(sB[cur] + boff[f]);
#pragma unroll
        for (int mf = 0; mf < 4; ++mf)
#pragma unroll
            for (int nf = 0; nf < 4; ++nf)
                acc[mf][nf] = MFMA16x16x32(av[mf], bw[nf], acc[mf][nf]);
        __syncthreads();
    }

#pragma unroll
    for (int nf = 0; nf < 4; ++nf) {
        const int n = n0 + wn * 64 + nf * 16 + li;
        const float bi = bo[n];
#pragma unroll
        for (int mf = 0; mf < 4; ++mf) {
#pragma unroll
            for (int r = 0; r < 4; ++r) {
                const int m = m0 + wm * 64 + mf * 16 + gg * 4 + r;
                out[(size_t)m * 512 + n] = acc[mf][nf][r] + bi;
            }
        }
    }
}

extern "C" void kernel_launch(void* const* d_in, const int* in_sizes, int n_in,
                              void* d_out, int out_size, void* d_ws, size_t ws_size,
                              hipStream_t stream) {
    const float* x  = (const float*)d_in[0];
    const float* Wq = (const float*)d_in[1];
    const float* bq = (const float*)d_in[2];
    const float* Wk = (const float*)d_in[3];
    const float* bk = (const float*)d_in[4];
    const float* Wv = (const float*)d_in[5];
    const float* bv = (const float*)d_in[6];
    const float* Wo = (const float*)d_in[7];
    const float* bo = (const float*)d_in[8];
    float* out = (float*)d_out;

    unsigned short* ws  = (unsigned short*)d_ws;
    unsigned short* xb  = ws;                  // 4096x1024
    unsigned short* Wqt = xb  + 4194304;       // 1024x1024
    unsigned short* Wkt = Wqt + 1048576;
    unsigned short* Wvt = Wkt + 1048576;
    unsigned short* Wot = Wvt + 1048576;       // 512x1024
    unsigned short* Qb  = Wot + 524288;        // [b][h][s][d]
    unsigned short* Kb  = Qb  + 4194304;
    unsigned short* Vb  = Kb  + 4194304;
    unsigned short* Vt  = Vb  + 4194304;       // [b][h][d][s]
    unsigned short* attnb = Vt + 4194304;      // [b][s][h][d]

    cvt_x_kernel<<<dim3(4096), dim3(256), 0, stream>>>(x, xb);
    tr_w_kernel<<<dim3(32, 32), dim3(32, 8), 0, stream>>>(Wq, Wqt, 1024);
    tr_w_kernel<<<dim3(32, 32), dim3(32, 8), 0, stream>>>(Wk, Wkt, 1024);
    tr_w_kernel<<<dim3(32, 32), dim3(32, 8), 0, stream>>>(Wv, Wvt, 1024);
    tr_w_kernel<<<dim3(32, 16), dim3(32, 8), 0, stream>>>(Wo, Wot, 512);
    gemm_qkv_kernel<<<dim3(24, 32), dim3(256), 0, stream>>>(xb, Wqt, Wkt, Wvt,
                                                            bq, bk, bv, Qb, Kb, Vb);
    tr_v_kernel<<<dim3(64, 2, 32), dim3(32, 8), 0, stream>>>(Vb, Vt);
    attn_kernel<<<dim3(16, 32), dim3(512), 0, stream>>>(Qb, Kb, Vt, attnb);
    gemm_out_kernel<<<dim3(4, 32), dim3(256), 0, stream>>>(attnb, Wot, bo, out);
}

// Round 4
// 129.500 us; speedup vs baseline: 1.7126x; 1.1432x over previous
//
#include <hip/hip_runtime.h>

typedef __attribute__((ext_vector_type(8))) __bf16 bf16x8;
typedef __attribute__((ext_vector_type(4))) __bf16 bf16x4;
typedef __attribute__((ext_vector_type(4))) float f32x4;

#define MFMA16x16x32(A, B, C) __builtin_amdgcn_mfma_f32_16x16x32_bf16(A, B, C, 0, 0, 0)

__device__ __forceinline__ unsigned short f2bf(float f) {
    unsigned int u = __float_as_uint(f);
    u += 0x7fffu + ((u >> 16) & 1u);
    return (unsigned short)(u >> 16);
}

__device__ __forceinline__ unsigned cvtpk_bf16(float lo, float hi) {
    unsigned r;
    asm("v_cvt_pk_bf16_f32 %0, %1, %2" : "=v"(r) : "v"(lo), "v"(hi));
    return r;
}

// raw hardware exp2 (v_exp_f32, ~1 ulp) — avoids OCML guarded sequence (~10 instr)
__device__ __forceinline__ float exp2_hw(float x) {
    float r;
    asm("v_exp_f32 %0, %1" : "=v"(r) : "v"(x));
    return r;
}

__device__ __forceinline__ void gload16(const void* src, void* lds) {
    __builtin_amdgcn_global_load_lds(
        (const __attribute__((address_space(1))) unsigned int*)src,
        (__attribute__((address_space(3))) unsigned int*)lds,
        16, 0, 0);
}

// ---------------- stage 1: x fp32 -> bf16 ----------------
__global__ __launch_bounds__(256) void cvt_x_kernel(const float* __restrict__ x,
                                                    unsigned short* __restrict__ xb) {
    const int i = (blockIdx.x * 256 + threadIdx.x) * 4;
    const float4 v = *(const float4*)(x + i);
    ushort4 o;
    o.x = f2bf(v.x); o.y = f2bf(v.y); o.z = f2bf(v.z); o.w = f2bf(v.w);
    *(ushort4*)(xb + i) = o;
}

// ---------------- stage 2: W [K][N] fp32 -> Wt [N][K=1024] bf16 ----------------
__global__ __launch_bounds__(256) void tr_w_kernel(const float* __restrict__ W,
                                                   unsigned short* __restrict__ Wt, int N) {
    __shared__ float tile[32][33];
    const int k0 = blockIdx.x * 32;
    const int n0 = blockIdx.y * 32;
    const int tx = threadIdx.x, ty = threadIdx.y;
#pragma unroll
    for (int i = 0; i < 4; ++i)
        tile[ty + 8 * i][tx] = W[(size_t)(k0 + ty + 8 * i) * N + n0 + tx];
    __syncthreads();
#pragma unroll
    for (int i = 0; i < 4; ++i)
        Wt[(size_t)(n0 + ty + 8 * i) * 1024 + k0 + tx] = f2bf(tile[tx][ty + 8 * i]);
}

// ---------------- stage 4: V [bh][s][64] -> Vt [bh][64][s] (bf16) ----------------
__global__ __launch_bounds__(256) void tr_v_kernel(const unsigned short* __restrict__ Vb,
                                                   unsigned short* __restrict__ Vt) {
    __shared__ unsigned short tile[32][33];
    const int bh = blockIdx.z;
    const int s0 = blockIdx.x * 32;
    const int d0 = blockIdx.y * 32;
    const int tx = threadIdx.x, ty = threadIdx.y;
#pragma unroll
    for (int i = 0; i < 4; ++i)
        tile[ty + 8 * i][tx] = Vb[((size_t)bh * 2048 + s0 + ty + 8 * i) * 64 + d0 + tx];
    __syncthreads();
#pragma unroll
    for (int i = 0; i < 4; ++i)
        Vt[((size_t)bh * 64 + d0 + ty + 8 * i) * 2048 + s0 + tx] = tile[tx][ty + 8 * i];
}

// ---------------- stage 3: fused QKV GEMM ----------------
// X [4096][1024] bf16  x  Wt [1024 n][1024 k] bf16  -> Q/K/V [b][h][s][d] bf16 (+bias)
// Q is pre-scaled by log2(e)/sqrt(DH) so attention softmax works in exp2 space.
__global__ __launch_bounds__(256, 2) void gemm_qkv_kernel(
    const unsigned short* __restrict__ xb,
    const unsigned short* __restrict__ Wqt,
    const unsigned short* __restrict__ Wkt,
    const unsigned short* __restrict__ Wvt,
    const float* __restrict__ bq, const float* __restrict__ bk, const float* __restrict__ bv,
    unsigned short* __restrict__ Qb, unsigned short* __restrict__ Kb, unsigned short* __restrict__ Vb)
{
    __shared__ unsigned short sA[2][128 * 32];
    __shared__ unsigned short sB[2][128 * 32];

    const int tid  = threadIdx.x;
    const int lane = tid & 63;
    const int w    = tid >> 6;
    const int wm   = w >> 1, wn = w & 1;
    const int li   = lane & 15, gg = lane >> 4;
    const int m0   = blockIdx.y * 128;
    const int which = blockIdx.x >> 3;
    const int nloc0 = (blockIdx.x & 7) * 128;

    const unsigned short* Wt = (which == 0) ? Wqt : ((which == 1) ? Wkt : Wvt);
    const float* bias        = (which == 0) ? bq  : ((which == 1) ? bk  : bv);
    unsigned short* dst      = (which == 0) ? Qb  : ((which == 1) ? Kb  : Vb);
    const float osc          = (which == 0) ? 0.18033688011112042f : 1.0f; // log2(e)/8

    const int srow = lane >> 2;   // row within 16-row chunk
    const int schk = lane & 3;    // 16B chunk within 64B row

    f32x4 acc[4][4];
#pragma unroll
    for (int i = 0; i < 4; ++i)
#pragma unroll
        for (int j = 0; j < 4; ++j)
            acc[i][j] = (f32x4){0.f, 0.f, 0.f, 0.f};

    int aoff[4], boff[4];
#pragma unroll
    for (int f = 0; f < 4; ++f) {
        const int ra = wm * 64 + f * 16 + li;
        aoff[f] = ra * 32 + ((gg ^ ((ra >> 1) & 3)) * 8);
        const int rb = wn * 64 + f * 16 + li;
        boff[f] = rb * 32 + ((gg ^ ((rb >> 1) & 3)) * 8);
    }

#pragma unroll
    for (int j = 0; j < 2; ++j) {
        const int rl = (w * 2 + j) * 16 + srow;
        const int c  = schk ^ ((rl >> 1) & 3);
        gload16(xb + (size_t)(m0 + rl) * 1024 + c * 8,   sA[0] + (w * 2 + j) * 512);
        gload16(Wt + (size_t)(nloc0 + rl) * 1024 + c * 8, sB[0] + (w * 2 + j) * 512);
    }
    __syncthreads();

    for (int kt = 0; kt < 32; ++kt) {
        const int cur = kt & 1;
        if (kt < 31) {
            const int k1 = (kt + 1) * 32;
#pragma unroll
            for (int j = 0; j < 2; ++j) {
                const int rl = (w * 2 + j) * 16 + srow;
                const int c  = schk ^ ((rl >> 1) & 3);
                gload16(xb + (size_t)(m0 + rl) * 1024 + k1 + c * 8,   sA[cur ^ 1] + (w * 2 + j) * 512);
                gload16(Wt + (size_t)(nloc0 + rl) * 1024 + k1 + c * 8, sB[cur ^ 1] + (w * 2 + j) * 512);
            }
        }
        bf16x8 av[4], bw[4];
#pragma unroll
        for (int f = 0; f < 4; ++f) av[f] = *(const bf16x8*)(sA[cur] + aoff[f]);
#pragma unroll
        for (int f = 0; f < 4; ++f) bw[f] = *(const bf16x8*)(sB[cur] + boff[f]);
#pragma unroll
        for (int mf = 0; mf < 4; ++mf)
#pragma unroll
            for (int nf = 0; nf < 4; ++nf)
                acc[mf][nf] = MFMA16x16x32(av[mf], bw[nf], acc[mf][nf]);
        __syncthreads();
    }

#pragma unroll
    for (int nf = 0; nf < 4; ++nf) {
        const int nl = nloc0 + wn * 64 + nf * 16 + li;
        const float bi = bias[nl];
        const int h = nl >> 6, d = nl & 63;
#pragma unroll
        for (int mf = 0; mf < 4; ++mf) {
#pragma unroll
            for (int r = 0; r < 4; ++r) {
                const int m = m0 + wm * 64 + mf * 16 + gg * 4 + r;
                const int b = m >> 11, s = m & 2047;
                dst[(((size_t)(b * 16 + h)) * 2048 + s) * 64 + d] = f2bf((acc[mf][nf][r] + bi) * osc);
            }
        }
    }
}

// ---------------- stage 5: flash attention v4 ----------------
// 512 threads = 8 waves, 16 q-rows per wave; grid 512 blocks, XCD-swizzled so
// each XCD owns 4 consecutive bh (K/V panels L2-resident). Raw v_exp_f32.
__global__ __launch_bounds__(512, 4) void attn_kernel(
    const unsigned short* __restrict__ Qb,
    const unsigned short* __restrict__ Kb,
    const unsigned short* __restrict__ Vt,
    unsigned short* __restrict__ Ob)
{
    __shared__ unsigned short sK[2][64 * 64];
    __shared__ unsigned short sV[2][64 * 64];
    __shared__ unsigned short sP[8][16 * 64];   // per-wave P tile [16 q][64 k], swizzled

    const int tid  = threadIdx.x;
    const int lane = tid & 63;
    const int w    = tid >> 6;        // 0..7
    const int li   = lane & 15, gg = lane >> 4;

    // XCD swizzle: 512 blocks, 8 XCDs round-robin on linear id -> give XCD c
    // the contiguous range v in [c*64, (c+1)*64) = 4 consecutive bh.
    const int L  = blockIdx.y * 16 + blockIdx.x;
    const int v  = (L & 7) * 64 + (L >> 3);
    const int bh = v >> 4;
    const int q0 = (v & 15) * 128 + w * 16;

    // staging: thread stages one 16B K chunk + one 16B V chunk (tile 64x64 each)
    const int slot = w * 64 + lane;          // 0..511
    const int srow = slot >> 3;              // 0..63
    const int schk = (slot & 7) ^ (srow & 7);

    char* const sPw = (char*)sP[w];
    const int swz = (li & 7) << 4;

    // Q fragments (pre-scaled by log2(e)/8) in registers for whole kernel
    bf16x8 qf[2];
#pragma unroll
    for (int kk = 0; kk < 2; ++kk) {
        const int q = q0 + li;
        const int d = kk * 32 + gg * 8;
        qf[kk] = *(const bf16x8*)(Qb + ((size_t)bh * 2048 + q) * 64 + d);
    }

    f32x4 acc[4];
#pragma unroll
    for (int df = 0; df < 4; ++df) acc[df] = (f32x4){0.f, 0.f, 0.f, 0.f};
    float m_s = -1e30f, l_s = 0.f;

    gload16(Kb + ((size_t)bh * 2048 + srow) * 64 + schk * 8, sK[0] + slot * 8);
    gload16(Vt + ((size_t)bh * 64 + srow) * 2048 + schk * 8, sV[0] + slot * 8);
    __syncthreads();

    for (int t = 0; t < 32; ++t) {
        const int cur = t & 1;
        if (t < 31) {
            gload16(Kb + ((size_t)bh * 2048 + (t + 1) * 64 + srow) * 64 + schk * 8,
                    sK[cur ^ 1] + slot * 8);
            gload16(Vt + ((size_t)bh * 64 + srow) * 2048 + (t + 1) * 64 + schk * 8,
                    sV[cur ^ 1] + slot * 8);
        }

        // ---- S^T = mfma(K, Q): st[nf], q = q0+li, k = nf*16 + gg*4 + r ----
        bf16x8 kf[4][2];
#pragma unroll
        for (int nf = 0; nf < 4; ++nf)
#pragma unroll
            for (int kk = 0; kk < 2; ++kk) {
                const int n = nf * 16 + li;
                const int ch = kk * 4 + gg;
                kf[nf][kk] = *(const bf16x8*)(sK[cur] + n * 64 + ((ch ^ (n & 7)) * 8));
            }
        f32x4 st[4];
#pragma unroll
        for (int nf = 0; nf < 4; ++nf) {
            st[nf] = (f32x4){0.f, 0.f, 0.f, 0.f};
            st[nf] = MFMA16x16x32(kf[nf][0], qf[0], st[nf]);
            st[nf] = MFMA16x16x32(kf[nf][1], qf[1], st[nf]);
        }

        // ---- online softmax with defer-max ----
        float t0 = fmaxf(fmaxf(st[0][0], st[0][1]), fmaxf(st[0][2], st[0][3]));
        float t1 = fmaxf(fmaxf(st[1][0], st[1][1]), fmaxf(st[1][2], st[1][3]));
        float t2 = fmaxf(fmaxf(st[2][0], st[2][1]), fmaxf(st[2][2], st[2][3]));
        float t3 = fmaxf(fmaxf(st[3][0], st[3][1]), fmaxf(st[3][2], st[3][3]));
        float tm = fmaxf(fmaxf(t0, t1), fmaxf(t2, t3));
        tm = fmaxf(tm, __shfl_xor(tm, 16, 64));
        tm = fmaxf(tm, __shfl_xor(tm, 32, 64));

        if (!__all(tm - m_s <= 8.0f)) {
            const float mnew = fmaxf(m_s, tm);
            const float alpha = exp2_hw(m_s - mnew);
            m_s = mnew;
            l_s *= alpha;
            float al[4];
#pragma unroll
            for (int r = 0; r < 4; ++r) al[r] = __shfl(alpha, gg * 4 + r, 64);
#pragma unroll
            for (int df = 0; df < 4; ++df)
#pragma unroll
                for (int r = 0; r < 4; ++r)
                    acc[df][r] *= al[r];
        }

        float rs = 0.f;
#pragma unroll
        for (int nf = 0; nf < 4; ++nf)
#pragma unroll
            for (int r = 0; r < 4; ++r) {
                const float p = exp2_hw(st[nf][r] - m_s);
                st[nf][r] = p;
                rs += p;
            }
        rs += __shfl_xor(rs, 16, 64);
        rs += __shfl_xor(rs, 32, 64);
        l_s += rs;

        // pack P (k-adjacent in r) and store 8B per nf, swizzled, wave-private
#pragma unroll
        for (int nf = 0; nf < 4; ++nf) {
            uint2 pv;
            pv.x = cvtpk_bf16(st[nf][0], st[nf][1]);
            pv.y = cvtpk_bf16(st[nf][2], st[nf][3]);
            const int byte = (li * 128 + nf * 32 + gg * 8) ^ swz;
            *(uint2*)(sPw + byte) = pv;
        }

        // ---- PV: O[q][d] += P[q][k] Vt[d][k] ----
        bf16x8 pf[2];
#pragma unroll
        for (int kk = 0; kk < 2; ++kk) {
            const int byte = (li * 128 + kk * 64 + gg * 16) ^ swz;
            pf[kk] = *(const bf16x8*)(sPw + byte);
        }
        bf16x8 vf[4][2];
#pragma unroll
        for (int df = 0; df < 4; ++df)
#pragma unroll
            for (int kk = 0; kk < 2; ++kk) {
                const int n = df * 16 + li;
                const int ch = kk * 4 + gg;
                vf[df][kk] = *(const bf16x8*)(sV[cur] + n * 64 + ((ch ^ (n & 7)) * 8));
            }
#pragma unroll
        for (int df = 0; df < 4; ++df) {
            acc[df] = MFMA16x16x32(pf[0], vf[df][0], acc[df]);
            acc[df] = MFMA16x16x32(pf[1], vf[df][1], acc[df]);
        }
        __syncthreads();
    }

    // epilogue: O = acc / l  -> attn buffer [b][s][h][d] (bf16)
    const int b = bh >> 4, h = bh & 15;
#pragma unroll
    for (int r = 0; r < 4; ++r) {
        const float lbc = __shfl(l_s, gg * 4 + r, 64);
        const float rl = 1.0f / lbc;
        const int q = q0 + gg * 4 + r;
#pragma unroll
        for (int df = 0; df < 4; ++df) {
            const int d = df * 16 + li;
            Ob[(((size_t)b * 2048 + q) * 16 + h) * 64 + d] = f2bf(acc[df][r] * rl);
        }
    }
}

// ---------------- stage 6: output projection (64x128 tile, 256 blocks) --------
__global__ __launch_bounds__(256, 2) void gemm_out_kernel(
    const unsigned short* __restrict__ attn,
    const unsigned short* __restrict__ Wot,
    const float* __restrict__ bo,
    float* __restrict__ out)
{
    __shared__ unsigned short sA[2][64 * 32];
    __shared__ unsigned short sB[2][128 * 32];

    const int tid  = threadIdx.x;
    const int lane = tid & 63;
    const int w    = tid >> 6;
    const int wm   = w >> 1, wn = w & 1;   // 2 m-waves x 2 n-waves
    const int li   = lane & 15, gg = lane >> 4;
    const int m0   = blockIdx.y * 64;
    const int n0   = blockIdx.x * 128;

    const int arow = tid >> 2;             // 0..63
    const int acol = tid & 3;

    f32x4 acc[2][4];
#pragma unroll
    for (int i = 0; i < 2; ++i)
#pragma unroll
        for (int j = 0; j < 4; ++j)
            acc[i][j] = (f32x4){0.f, 0.f, 0.f, 0.f};

    int aoff[2], boff[4];
#pragma unroll
    for (int f = 0; f < 2; ++f) {
        const int ra = wm * 32 + f * 16 + li;
        aoff[f] = ra * 32 + ((gg ^ ((ra >> 1) & 3)) * 8);
    }
#pragma unroll
    for (int f = 0; f < 4; ++f) {
        const int rb = wn * 64 + f * 16 + li;
        boff[f] = rb * 32 + ((gg ^ ((rb >> 1) & 3)) * 8);
    }

    {
        const int ca = acol ^ ((arow >> 1) & 3);
        gload16(attn + (size_t)(m0 + arow) * 1024 + ca * 8, sA[0] + tid * 8);
#pragma unroll
        for (int jj = 0; jj < 2; ++jj) {
            const int rb = jj * 64 + arow;
            const int cb = acol ^ ((rb >> 1) & 3);
            gload16(Wot + (size_t)(n0 + rb) * 1024 + cb * 8, sB[0] + (jj * 256 + tid) * 8);
        }
    }
    __syncthreads();

    for (int kt = 0; kt < 32; ++kt) {
        const int cur = kt & 1;
        if (kt < 31) {
            const int k1 = (kt + 1) * 32;
            const int ca = acol ^ ((arow >> 1) & 3);
            gload16(attn + (size_t)(m0 + arow) * 1024 + k1 + ca * 8, sA[cur ^ 1] + tid * 8);
#pragma unroll
            for (int jj = 0; jj < 2; ++jj) {
                const int rb = jj * 64 + arow;
                const int cb = acol ^ ((rb >> 1) & 3);
                gload16(Wot + (size_t)(n0 + rb) * 1024 + k1 + cb * 8, sB[cur ^ 1] + (jj * 256 + tid) * 8);
            }
        }
        bf16x8 av[2], bw[4];
#pragma unroll
        for (int f = 0; f < 2; ++f) av[f] = *(const bf16x8*)(sA[cur] + aoff[f]);
#pragma unroll
        for (int f = 0; f < 4; ++f) bw[f] = *(const bf16x8*)(sB[cur] + boff[f]);
#pragma unroll
        for (int mf = 0; mf < 2; ++mf)
#pragma unroll
            for (int nf = 0; nf < 4; ++nf)
                acc[mf][nf] = MFMA16x16x32(av[mf], bw[nf], acc[mf][nf]);
        __syncthreads();
    }

#pragma unroll
    for (int nf = 0; nf < 4; ++nf) {
        const int n = n0 + wn * 64 + nf * 16 + li;
        const float bi = bo[n];
#pragma unroll
        for (int mf = 0; mf < 2; ++mf) {
#pragma unroll
            for (int r = 0; r < 4; ++r) {
                const int m = m0 + wm * 32 + mf * 16 + gg * 4 + r;
                out[(size_t)m * 512 + n] = acc[mf][nf][r] + bi;
            }
        }
    }
}

extern "C" void kernel_launch(void* const* d_in, const int* in_sizes, int n_in,
                              void* d_out, int out_size, void* d_ws, size_t ws_size,
                              hipStream_t stream) {
    const float* x  = (const float*)d_in[0];
    const float* Wq = (const float*)d_in[1];
    const float* bq = (const float*)d_in[2];
    const float* Wk = (const float*)d_in[3];
    const float* bk = (const float*)d_in[4];
    const float* Wv = (const float*)d_in[5];
    const float* bv = (const float*)d_in[6];
    const float* Wo = (const float*)d_in[7];
    const float* bo = (const float*)d_in[8];
    float* out = (float*)d_out;

    unsigned short* ws  = (unsigned short*)d_ws;
    unsigned short* xb  = ws;                  // 4096x1024
    unsigned short* Wqt = xb  + 4194304;       // 1024x1024
    unsigned short* Wkt = Wqt + 1048576;
    unsigned short* Wvt = Wkt + 1048576;
    unsigned short* Wot = Wvt + 1048576;       // 512x1024
    unsigned short* Qb  = Wot + 524288;        // [b][h][s][d]
    unsigned short* Kb  = Qb  + 4194304;
    unsigned short* Vb  = Kb  + 4194304;
    unsigned short* Vt  = Vb  + 4194304;       // [b][h][d][s]
    unsigned short* attnb = Vt + 4194304;      // [b][s][h][d]

    cvt_x_kernel<<<dim3(4096), dim3(256), 0, stream>>>(x, xb);
    tr_w_kernel<<<dim3(32, 32), dim3(32, 8), 0, stream>>>(Wq, Wqt, 1024);
    tr_w_kernel<<<dim3(32, 32), dim3(32, 8), 0, stream>>>(Wk, Wkt, 1024);
    tr_w_kernel<<<dim3(32, 32), dim3(32, 8), 0, stream>>>(Wv, Wvt, 1024);
    tr_w_kernel<<<dim3(32, 16), dim3(32, 8), 0, stream>>>(Wo, Wot, 512);
    gemm_qkv_kernel<<<dim3(24, 32), dim3(256), 0, stream>>>(xb, Wqt, Wkt, Wvt,
                                                            bq, bk, bv, Qb, Kb, Vb);
    tr_v_kernel<<<dim3(64, 2, 32), dim3(32, 8), 0, stream>>>(Vb, Vt);
    attn_kernel<<<dim3(16, 32), dim3(512), 0, stream>>>(Qb, Kb, Vt, attnb);
    gemm_out_kernel<<<dim3(4, 64), dim3(256), 0, stream>>>(attnb, Wot, bo, out);
}